// Round 12
// baseline (1163.166 us; speedup 1.0000x reference)
//
#include <hip/hip_runtime.h>

#define DD 128
#define ND_REP      25   // measurement reps (idempotent kernels)
#define SCAN_REP    64
#define SCATTER_REP 40

typedef float vfloat4 __attribute__((ext_vector_type(4)));
typedef __attribute__((ext_vector_type(8))) short short8;   // 8 bf16 = 4 VGPRs
typedef __attribute__((ext_vector_type(4))) float f32x4;    // MFMA accumulator

__device__ inline float4 ntload4(const float* p) {
    vfloat4 v = __builtin_nontemporal_load(reinterpret_cast<const vfloat4*>(p));
    return make_float4(v.x, v.y, v.z, v.w);
}

// round-to-nearest-even f32 -> bf16 (as ushort)
__device__ inline ushort f2bf(float f) {
    unsigned x = __float_as_uint(f);
    return (ushort)((x + 0x7FFFu + ((x >> 16) & 1u)) >> 16);
}

// ---------------------------------------------------------------------------
// K1: per-node dots s[n]=h·aw_src, t[n]=h·aw_dst+attn_b; zeroes count[n];
// writes h16. Tail blocks cast W -> W16. Idempotent -> rep'd for measurement.
// ---------------------------------------------------------------------------
__global__ __launch_bounds__(256) void k_node_dots(
    const float* __restrict__ h, const float* __restrict__ attn_w,
    const float* __restrict__ attn_b,
    float* __restrict__ s, float* __restrict__ t,
    int* __restrict__ count, ushort* __restrict__ h16,
    int n_nodes, int n_node_blocks,
    const float* __restrict__ W, ushort* __restrict__ W16)
{
    for (int rep = 0; rep < ND_REP; ++rep) {
        if (blockIdx.x >= n_node_blocks) {
            int idx = (blockIdx.x - n_node_blocks) * 256 + threadIdx.x;
            if (idx < 128 * 256) W16[idx] = f2bf(W[idx]);
        } else {
            int gid  = blockIdx.x * blockDim.x + threadIdx.x;
            int node = gid >> 6;
            int lane = threadIdx.x & 63;
            if (node < n_nodes) {
                const float2 hv = *reinterpret_cast<const float2*>(h + (size_t)node * DD + lane * 2);
                const float2 as = *reinterpret_cast<const float2*>(attn_w + lane * 2);
                const float2 ad = *reinterpret_cast<const float2*>(attn_w + DD + lane * 2);
                ushort2 hb; hb.x = f2bf(hv.x); hb.y = f2bf(hv.y);
                *reinterpret_cast<ushort2*>(h16 + (size_t)node * DD + lane * 2) = hb;
                float sa = hv.x * as.x + hv.y * as.y;
                float ta = hv.x * ad.x + hv.y * ad.y;
                #pragma unroll
                for (int off = 32; off > 0; off >>= 1) {
                    sa += __shfl_down(sa, off);
                    ta += __shfl_down(ta, off);
                }
                if (lane == 0) { s[node] = sa; t[node] = ta + attn_b[0]; count[node] = 0; }
            }
        }
        asm volatile("" ::: "memory");
    }
}

// ---------------------------------------------------------------------------
// K2: histogram + per-edge rank (native int atomics) — NOT rep'd (stateful);
// its time = total minus everything else.
// ---------------------------------------------------------------------------
__global__ __launch_bounds__(256) void k_hist(
    const int* __restrict__ dst, int* __restrict__ count,
    int* __restrict__ rank, int n_edges)
{
    int e = blockIdx.x * blockDim.x + threadIdx.x;
    if (e >= n_edges) return;
    rank[e] = atomicAdd(count + dst[e], 1);
}

// ---------------------------------------------------------------------------
// K3: single-kernel exclusive scan: each block sums all counts before its
// chunk (L2-hot strided reads), then scans its own 256. Replaces the old
// 2-kernel scan. Idempotent -> rep'd for measurement.
// ---------------------------------------------------------------------------
__global__ __launch_bounds__(256) void k_scan(
    const int* __restrict__ count, int* __restrict__ offset,
    int n, int n_edges)
{
    __shared__ int sm[256];
    int tid = threadIdx.x;
    for (int rep = 0; rep < SCAN_REP; ++rep) {
        int limit = blockIdx.x * 256;
        int acc = 0;
        for (int i = tid; i < limit; i += 256) acc += count[i];
        sm[tid] = acc; __syncthreads();
        for (int off = 128; off > 0; off >>= 1) {
            if (tid < off) sm[tid] += sm[tid + off];
            __syncthreads();
        }
        int base = sm[0];
        __syncthreads();
        int idx = limit + tid;
        int c = (idx < n) ? count[idx] : 0;
        sm[tid] = c; __syncthreads();
        for (int off = 1; off < 256; off <<= 1) {
            int t2 = (tid >= off) ? sm[tid - off] : 0;
            __syncthreads();
            sm[tid] += t2;
            __syncthreads();
        }
        if (idx < n) offset[idx] = base + sm[tid] - c;
        if (idx == 0) offset[n] = n_edges;
        __syncthreads();
        asm volatile("" ::: "memory");
    }
}

// ---------------------------------------------------------------------------
// K4: scatter {edge id, relu score} int2 into dst-sorted position.
// Idempotent -> rep'd for measurement.
// ---------------------------------------------------------------------------
__global__ __launch_bounds__(256) void k_scatter_ids(
    const int* __restrict__ dst, const int* __restrict__ src,
    const int* __restrict__ rank, const int* __restrict__ offset,
    const float* __restrict__ s, const float* __restrict__ t,
    int2* __restrict__ os, int n_edges)
{
    int e = blockIdx.x * blockDim.x + threadIdx.x;
    if (e >= n_edges) return;
    for (int rep = 0; rep < SCATTER_REP; ++rep) {
        int d   = dst[e];
        int pos = offset[d] + rank[e];
        float sc = fmaxf(s[src[e]] + t[d], 0.f);
        int2 v; v.x = e; v.y = __float_as_int(sc);
        os[pos] = v;
        asm volatile("" ::: "memory");
    }
}

// ---------------------------------------------------------------------------
// K5: fused per-node attention (measured ~64 us, HBM roofline). bf16 z out.
// ---------------------------------------------------------------------------
__global__ __launch_bounds__(256) void k_fused(
    const int* __restrict__ offset, const int2* __restrict__ os,
    const float* __restrict__ ef,
    ushort* __restrict__ u16, int n_nodes)
{
    int node = blockIdx.x * (blockDim.x >> 6) + (threadIdx.x >> 6);
    int lane = threadIdx.x & 63;
    if (node >= n_nodes) return;
    int beg = offset[node];
    int deg = offset[node + 1] - beg;

    if (deg <= 64) {
        int2 os_l = make_int2(0, 0);
        if (lane < deg) os_l = os[beg + lane];
        int   e_l = os_l.x;
        float pe  = (lane < deg) ? expf(__int_as_float(os_l.y)) : 0.f;
        float sum = pe;
        #pragma unroll
        for (int off = 32; off > 0; off >>= 1) sum += __shfl_xor(sum, off);
        float inv  = sum > 0.f ? 1.f / sum : 0.f;
        float pw_l = pe * inv;

        int grp = lane >> 3, sub = lane & 7;
        float4 a0 = make_float4(0.f, 0.f, 0.f, 0.f);
        float4 a1 = a0, a2 = a0, a3 = a0;
        int kmax = (deg + 7) >> 3;
        for (int k = 0; k < kmax; ++k) {
            int j  = grp + 8 * k;
            int jj = (j < deg) ? j : 0;
            int   e  = __shfl(e_l, jj);
            float pw = __shfl(pw_l, jj);
            if (j < deg) {
                const float* er = ef + (size_t)e * DD;
                float4 v0 = ntload4(er + sub * 4);
                float4 v1 = ntload4(er + 32 + sub * 4);
                float4 v2 = ntload4(er + 64 + sub * 4);
                float4 v3 = ntload4(er + 96 + sub * 4);
                a0.x = fmaf(pw, v0.x, a0.x); a0.y = fmaf(pw, v0.y, a0.y);
                a0.z = fmaf(pw, v0.z, a0.z); a0.w = fmaf(pw, v0.w, a0.w);
                a1.x = fmaf(pw, v1.x, a1.x); a1.y = fmaf(pw, v1.y, a1.y);
                a1.z = fmaf(pw, v1.z, a1.z); a1.w = fmaf(pw, v1.w, a1.w);
                a2.x = fmaf(pw, v2.x, a2.x); a2.y = fmaf(pw, v2.y, a2.y);
                a2.z = fmaf(pw, v2.z, a2.z); a2.w = fmaf(pw, v2.w, a2.w);
                a3.x = fmaf(pw, v3.x, a3.x); a3.y = fmaf(pw, v3.y, a3.y);
                a3.z = fmaf(pw, v3.z, a3.z); a3.w = fmaf(pw, v3.w, a3.w);
            }
        }
        #pragma unroll
        for (int off = 8; off <= 32; off <<= 1) {
            a0.x += __shfl_xor(a0.x, off); a0.y += __shfl_xor(a0.y, off);
            a0.z += __shfl_xor(a0.z, off); a0.w += __shfl_xor(a0.w, off);
            a1.x += __shfl_xor(a1.x, off); a1.y += __shfl_xor(a1.y, off);
            a1.z += __shfl_xor(a1.z, off); a1.w += __shfl_xor(a1.w, off);
            a2.x += __shfl_xor(a2.x, off); a2.y += __shfl_xor(a2.y, off);
            a2.z += __shfl_xor(a2.z, off); a2.w += __shfl_xor(a2.w, off);
            a3.x += __shfl_xor(a3.x, off); a3.y += __shfl_xor(a3.y, off);
            a3.z += __shfl_xor(a3.z, off); a3.w += __shfl_xor(a3.w, off);
        }
        if (lane < 8) {
            ushort* ur = u16 + (size_t)node * DD;
            *reinterpret_cast<ushort4*>(ur + 4 * sub) =
                make_ushort4(f2bf(a0.x), f2bf(a0.y), f2bf(a0.z), f2bf(a0.w));
            *reinterpret_cast<ushort4*>(ur + 32 + 4 * sub) =
                make_ushort4(f2bf(a1.x), f2bf(a1.y), f2bf(a1.z), f2bf(a1.w));
            *reinterpret_cast<ushort4*>(ur + 64 + 4 * sub) =
                make_ushort4(f2bf(a2.x), f2bf(a2.y), f2bf(a2.z), f2bf(a2.w));
            *reinterpret_cast<ushort4*>(ur + 96 + 4 * sub) =
                make_ushort4(f2bf(a3.x), f2bf(a3.y), f2bf(a3.z), f2bf(a3.w));
        }
    } else {
        float sum = 0.f;
        for (int i = lane; i < deg; i += 64) {
            int2 v = os[beg + i];
            sum += expf(__int_as_float(v.y));
        }
        #pragma unroll
        for (int off = 32; off > 0; off >>= 1) sum += __shfl_xor(sum, off);
        float inv = sum > 0.f ? 1.f / sum : 0.f;

        float2 acc = make_float2(0.f, 0.f);
        for (int i0 = 0; i0 < deg; i0 += 64) {
            int cnt = min(64, deg - i0);
            int2 v = make_int2(0, 0);
            if (lane < cnt) v = os[beg + i0 + lane];
            int   e_l = v.x;
            float p_l = (lane < cnt) ? expf(__int_as_float(v.y)) * inv : 0.f;
            for (int j = 0; j < cnt; ++j) {
                int   e  = __shfl(e_l, j);
                float pw = __shfl(p_l, j);
                float2 vv = *reinterpret_cast<const float2*>(ef + (size_t)e * DD + lane * 2);
                acc.x = fmaf(pw, vv.x, acc.x);
                acc.y = fmaf(pw, vv.y, acc.y);
            }
        }
        ushort2 uu; uu.x = f2bf(acc.x); uu.y = f2bf(acc.y);
        *reinterpret_cast<ushort2*>(u16 + (size_t)node * DD + lane * 2) = uu;
    }
}

// ---------------------------------------------------------------------------
// K6: out = relu([h16|u16] @ W16^T + b) via bf16 MFMA (verified round 11)
// ---------------------------------------------------------------------------
__global__ __launch_bounds__(256) void k_apply_mfma(
    const ushort* __restrict__ h16, const ushort* __restrict__ u16,
    const ushort* __restrict__ W16, const float* __restrict__ b,
    float* __restrict__ out, int n_nodes)
{
    int wave = threadIdx.x >> 6;
    int lane = threadIdx.x & 63;
    int nodeBase = blockIdx.x * 64 + wave * 16;
    int row  = lane & 15;
    int quad = lane >> 4;
    int node = nodeBase + row;
    if (node >= n_nodes) node = n_nodes - 1;   // clamp loads; stores guarded

    f32x4 acc[8];
    #pragma unroll
    for (int ct = 0; ct < 8; ++ct) acc[ct] = (f32x4){0.f, 0.f, 0.f, 0.f};

    #pragma unroll
    for (int kc = 0; kc < 8; ++kc) {
        const ushort* abase = (kc < 4)
            ? (h16 + (size_t)node * DD + kc * 32 + quad * 8)
            : (u16 + (size_t)node * DD + (kc - 4) * 32 + quad * 8);
        short8 a = *reinterpret_cast<const short8*>(abase);
        #pragma unroll
        for (int ct = 0; ct < 8; ++ct) {
            const ushort* wb = W16 + ((size_t)(ct * 16 + row)) * 256 + kc * 32 + quad * 8;
            short8 bb = *reinterpret_cast<const short8*>(wb);
            acc[ct] = __builtin_amdgcn_mfma_f32_16x16x32_bf16(a, bb, acc[ct], 0, 0, 0);
        }
    }

    #pragma unroll
    for (int ct = 0; ct < 8; ++ct) {
        int col = ct * 16 + row;
        float bk = b[col];
        #pragma unroll
        for (int r = 0; r < 4; ++r) {
            int n = nodeBase + quad * 4 + r;
            if (n < n_nodes)
                out[(size_t)n * DD + col] = fmaxf(acc[ct][r] + bk, 0.f);
        }
    }
}

// ---------------------------------------------------------------------------
extern "C" void kernel_launch(void* const* d_in, const int* in_sizes, int n_in,
                              void* d_out, int out_size, void* d_ws, size_t ws_size,
                              hipStream_t stream)
{
    const float* nfeats = (const float*)d_in[0];
    const float* efeats = (const float*)d_in[1];
    const float* W      = (const float*)d_in[2];
    const float* Wb     = (const float*)d_in[3];
    const float* attn_w = (const float*)d_in[4];
    const float* attn_b = (const float*)d_in[5];
    const int*   src    = (const int*)d_in[6];
    const int*   dst    = (const int*)d_in[7];

    const int n_nodes = in_sizes[0] / DD;
    const int n_edges = in_sizes[6];
    const int NB  = (n_nodes + 255) / 256;
    const int NDB = (n_nodes + 3) / 4;

    // workspace layout (os_buf 8B-aligned)
    char* wsb = (char*)d_ws;
    float*  s_buf  = (float*)wsb;                        wsb += (size_t)n_nodes * 4;
    float*  t_buf  = (float*)wsb;                        wsb += (size_t)n_nodes * 4;
    int*    count  = (int*)wsb;                          wsb += (size_t)n_nodes * 4;
    int*    offset = (int*)wsb;                          wsb += (size_t)(n_nodes + 2) * 4;
    int2*   os_buf = (int2*)wsb;                         wsb += (size_t)n_edges * 8;
    ushort* h16    = (ushort*)wsb;                       wsb += (size_t)n_nodes * DD * 2;
    ushort* u16    = (ushort*)wsb;                       wsb += (size_t)n_nodes * DD * 2;
    ushort* W16    = (ushort*)wsb;                       wsb += (size_t)128 * 256 * 2;
    int*    rank   = (int*)u16;   // aliased: rank dead before k_fused writes u16

    k_node_dots<<<NDB + 128, 256, 0, stream>>>(nfeats, attn_w, attn_b, s_buf, t_buf,
                                               count, h16, n_nodes, NDB, W, W16);
    k_hist<<<(n_edges + 255) / 256, 256, 0, stream>>>(dst, count, rank, n_edges);
    k_scan<<<NB, 256, 0, stream>>>(count, offset, n_nodes, n_edges);
    k_scatter_ids<<<(n_edges + 255) / 256, 256, 0, stream>>>(dst, src, rank, offset,
                                                             s_buf, t_buf,
                                                             os_buf, n_edges);

    k_fused<<<(n_nodes + 3) / 4, 256, 0, stream>>>(offset, os_buf, efeats, u16, n_nodes);

    k_apply_mfma<<<(n_nodes + 63) / 64, 256, 0, stream>>>(h16, u16, W16, Wb,
                                                          (float*)d_out, n_nodes);
}